// Round 8
// baseline (137.475 us; speedup 1.0000x reference)
//
#include <hip/hip_runtime.h>
#include <hip/hip_bf16.h>
#include <math.h>

#define NPATH 6
#define NINST 20000
#define PLEN 4
#define DFEAT 128
#define TPB1 256            // threads per pass1 block
#define WPB 4               // waves per block
#define GPW 4               // instance-groups per wave (16 lanes each)
#define GPB (WPB * GPW)     // 16 groups per block
#define BPP 128             // blocks per path
#define GPP (BPP * GPB)     // 2048 instance streams per path
#define RESCALE_THR 8.0f

__device__ __forceinline__ float dot4(float4 a, float4 b) {
    return a.x * b.x + a.y * b.y + a.z * b.z + a.w * b.w;
}

// ---------------------------------------------------------------------------
// Pass 1 (byte-identical to the proven r5 kernel): fused u-precompute +
// online-softmax gather, 2-deep software pipeline, defer-max rescale.
// grid = NPATH*BPP x TPB1
// ---------------------------------------------------------------------------
__global__ __launch_bounds__(TPB1, 4) void k_pass1(
    const float* __restrict__ feat, const int* __restrict__ inst,
    const float* __restrict__ W_enc, const float* __restrict__ b_enc,
    const float* __restrict__ W_att, const float* __restrict__ b_att,
    const int* __restrict__ etype,
    float* __restrict__ pV, float* __restrict__ pM, float* __restrict__ pS)
{
    int m    = blockIdx.x / BPP;
    int bw   = blockIdx.x % BPP;
    int tid  = threadIdx.x;
    int wv   = tid >> 6, lane = tid & 63;
    int grp  = lane >> 4, sub = lane & 15;
    int gid  = wv * GPW + grp;              // group within block [0,16)
    int g    = bw * GPB + gid;              // stream id within path [0,2048)

    __shared__ float swa[2 * DFEAT];
    __shared__ float su1[DFEAT], su2[DFEAT];
    __shared__ float sbc[DFEAT];
    __shared__ float scv;
    __shared__ float sV[GPB][DFEAT + 4];
    __shared__ float sMx[GPB], sSm[GPB];

    // ---- prologue: issue idx + two row-sets immediately ----
    const int4* ib4 = (const int4*)(inst + (size_t)m * NINST * PLEN);
    int i = g;
    int4 j0 = ib4[i];
    int4 j1 = ib4[i + GPP];
    int4 j2 = ib4[i + 2 * GPP];             // g+4096 < 20000 always

    const float4* r0 = (const float4*)(feat + (size_t)j0.x * DFEAT);
    const float4* r3 = (const float4*)(feat + (size_t)j0.w * DFEAT);
    float4 A0a = r0[sub], A0b = r0[sub + 16];
    float4 A3a = r3[sub], A3b = r3[sub + 16];
    const float4* q0 = (const float4*)(feat + (size_t)j1.x * DFEAT);
    const float4* q3 = (const float4*)(feat + (size_t)j1.w * DFEAT);
    float4 B0a = q0[sub], B0b = q0[sub + 16];
    float4 B3a = q3[sub], B3b = q3[sub + 16];

    // ---- u1/u2/c in LDS (overlaps the in-flight gathers) ----
    int e = etype[m];
    swa[tid] = W_att[(size_t)e * (2 * DFEAT) + tid];    // TPB1 == 2*DFEAT
    __syncthreads();
    if (tid < DFEAT) {
        const float4* Wr = (const float4*)(W_enc + ((size_t)m * DFEAT + tid) * DFEAT);
        float s1 = 0.f, s2 = 0.f;
        #pragma unroll 8
        for (int q = 0; q < DFEAT / 4; ++q) {
            float4 w4 = Wr[q];
            s1 += w4.x * swa[4*q]         + w4.y * swa[4*q+1]
                + w4.z * swa[4*q+2]       + w4.w * swa[4*q+3];
            s2 += w4.x * swa[DFEAT+4*q]   + w4.y * swa[DFEAT+4*q+1]
                + w4.z * swa[DFEAT+4*q+2] + w4.w * swa[DFEAT+4*q+3];
        }
        su1[tid] = s1;
        su2[tid] = s2;
        sbc[tid] = b_enc[m * DFEAT + tid] * (swa[tid] + swa[DFEAT + tid]);
    }
    __syncthreads();
    if (tid < 64) {
        float t = sbc[tid] + sbc[tid + 64];
        #pragma unroll
        for (int o = 32; o; o >>= 1) t += __shfl_xor(t, o);
        if (tid == 0) scv = t + b_att[e];
    }
    __syncthreads();

    float4 U1a = ((const float4*)su1)[sub], U1b = ((const float4*)su1)[sub + 16];
    float4 U2a = ((const float4*)su2)[sub], U2b = ((const float4*)su2)[sub + 16];
    float c = scv;

    float mref = 0.f, tmax = -3e38f, sum = 0.f;
    float4 va = make_float4(0.f, 0.f, 0.f, 0.f);
    float4 vb = make_float4(0.f, 0.f, 0.f, 0.f);

#define COMPUTE(R0a, R0b, R3a, R3b)                                          \
    {                                                                        \
        float p = dot4(R0a, U1a) + dot4(R0b, U1b)                            \
                + dot4(R3a, U2a) + dot4(R3b, U2b);                           \
        p += __shfl_xor(p, 1);                                               \
        p += __shfl_xor(p, 2);                                               \
        p += __shfl_xor(p, 4);                                               \
        p += __shfl_xor(p, 8);                                               \
        float s = p + c;                                                     \
        s = s > 0.f ? s : 0.2f * s;                                          \
        tmax = fmaxf(tmax, s);                                               \
        if (tmax > mref + RESCALE_THR) {                                     \
            float r = __expf(mref - tmax);                                   \
            sum *= r;                                                        \
            va.x *= r; va.y *= r; va.z *= r; va.w *= r;                      \
            vb.x *= r; vb.y *= r; vb.z *= r; vb.w *= r;                      \
            mref = tmax;                                                     \
        }                                                                    \
        float pe = __expf(s - mref);                                         \
        sum += pe;                                                           \
        va.x += pe * R3a.x; va.y += pe * R3a.y;                              \
        va.z += pe * R3a.z; va.w += pe * R3a.w;                              \
        vb.x += pe * R3b.x; vb.y += pe * R3b.y;                              \
        vb.z += pe * R3b.z; vb.w += pe * R3b.w;                              \
    }

    // ---- guard-free main loop ----
    while (i + 2 * GPP < NINST) {
        const float4* p0 = (const float4*)(feat + (size_t)j2.x * DFEAT);
        const float4* p3 = (const float4*)(feat + (size_t)j2.w * DFEAT);
        float4 C0a = p0[sub], C0b = p0[sub + 16];
        float4 C3a = p3[sub], C3b = p3[sub + 16];
        int nj = i + 3 * GPP;
        nj = nj < NINST ? nj : NINST - 1;
        int4 j3 = ib4[nj];

        COMPUTE(A0a, A0b, A3a, A3b);

        A0a = B0a; A0b = B0b; A3a = B3a; A3b = B3b;
        B0a = C0a; B0b = C0b; B3a = C3a; B3b = C3b;
        j2 = j3;
        i += GPP;
    }
    COMPUTE(A0a, A0b, A3a, A3b);
    i += GPP;
    if (i < NINST) COMPUTE(B0a, B0b, B3a, B3b);
#undef COMPUTE

    // ---- block-level flash combine of 16 group states ----
    *(float4*)&sV[gid][sub * 4]      = va;
    *(float4*)&sV[gid][64 + sub * 4] = vb;
    if (sub == 0) { sMx[gid] = mref; sSm[gid] = sum; }
    __syncthreads();

    if (tid < DFEAT) {
        float M = sMx[0];
        #pragma unroll
        for (int k = 1; k < GPB; ++k) M = fmaxf(M, sMx[k]);
        float S = 0.f, V = 0.f;
        #pragma unroll
        for (int k = 0; k < GPB; ++k) {
            float ek = __expf(sMx[k] - M);
            S += ek * sSm[k];
            V += ek * sV[k][tid];
        }
        pV[(size_t)blockIdx.x * DFEAT + tid] = V;
        if (tid == 0) { pM[blockIdx.x] = M; pS[blockIdx.x] = S; }
    }
}

// ---------------------------------------------------------------------------
// Tail: ONE block, 512 threads. For each path m: flash-combine the 128 block
// partials, normalize, GEMV with W_enc -> mp[m], ms[m] (kept in LDS). Then
// the 6-path softmax + blend + ELU, written straight to out. No atomics, no
// fences, no memset.
// ---------------------------------------------------------------------------
__global__ __launch_bounds__(512) void k_tail(
    const float* __restrict__ pV, const float* __restrict__ pM, const float* __restrict__ pS,
    const float* __restrict__ W_enc, const float* __restrict__ b_enc,
    const float* __restrict__ w_mp, const float* __restrict__ b_mp,
    float* __restrict__ out)
{
    int tid = threadIdx.x;
    int d = tid & 127, slice = tid >> 7;    // 4 slices

    __shared__ float tmp[BPP];
    __shared__ float eL[BPP];
    __shared__ float sv[4][DFEAT];
    __shared__ float sVn[DFEAT];
    __shared__ float mpAll[NPATH][DFEAT];
    __shared__ float smsv[NPATH];
    __shared__ float sS, sMx;

    for (int m = 0; m < NPATH; ++m) {
        // 1) M = max over 128 block maxima
        if (tid < BPP) tmp[tid] = pM[m * BPP + tid];
        __syncthreads();
        for (int off = 64; off; off >>= 1) {
            if (tid < off) tmp[tid] = fmaxf(tmp[tid], tmp[tid + off]);
            __syncthreads();
        }
        if (tid == 0) sMx = tmp[0];
        __syncthreads();
        float M = sMx;

        // 2) e_k, S
        if (tid < BPP) {
            float ek = __expf(pM[m * BPP + tid] - M);
            eL[tid] = ek;
            tmp[tid] = ek * pS[m * BPP + tid];
        }
        __syncthreads();
        for (int off = 64; off; off >>= 1) {
            if (tid < off) tmp[tid] += tmp[tid + off];
            __syncthreads();
        }
        if (tid == 0) sS = tmp[0];
        __syncthreads();
        float Sinv = 1.f / sS;

        // 3) V[d] = sum_k e_k * pV[k][d]
        float acc = 0.f;
        for (int k = slice; k < BPP; k += 4)
            acc += eL[k] * pV[((size_t)(m * BPP + k)) * DFEAT + d];
        sv[slice][d] = acc;
        __syncthreads();
        if (tid < DFEAT)
            sVn[tid] = (sv[0][tid] + sv[1][tid] + sv[2][tid] + sv[3][tid]) * Sinv;
        __syncthreads();

        // 4) GEMV: mp[h] = sVn . W[:,h] + b_enc[m][h]
        const float* W = W_enc + (size_t)m * DFEAT * DFEAT;
        float g = 0.f;
        for (int dd = slice; dd < DFEAT; dd += 4)
            g += sVn[dd] * W[(size_t)dd * DFEAT + d];
        __syncthreads();
        sv[slice][d] = g;
        __syncthreads();
        if (tid < DFEAT) {
            float t = sv[0][tid] + sv[1][tid] + sv[2][tid] + sv[3][tid]
                    + b_enc[m * DFEAT + tid];
            mpAll[m][tid] = t;
            tmp[tid] = t * w_mp[tid];
        }
        __syncthreads();

        // 5) ms[m] = mp . w_mp + b_mp
        if (tid < 64) {
            float t = tmp[tid] + tmp[tid + 64];
            #pragma unroll
            for (int o = 32; o; o >>= 1) t += __shfl_xor(t, o);
            if (tid == 0) smsv[m] = t + b_mp[0];
        }
        __syncthreads();
    }

    // ---- 6-path softmax + blend + ELU ----
    if (tid < DFEAT) {
        float l[NPATH], mx = -3e38f;
        #pragma unroll
        for (int k = 0; k < NPATH; ++k) {
            float x = smsv[k];
            x = x > 0.f ? x : 0.2f * x;
            l[k] = x;
            mx = fmaxf(mx, x);
        }
        float s = 0.f;
        #pragma unroll
        for (int k = 0; k < NPATH; ++k) { l[k] = __expf(l[k] - mx); s += l[k]; }
        float o = 0.f;
        #pragma unroll
        for (int k = 0; k < NPATH; ++k) o += (l[k] / s) * mpAll[k][tid];
        out[tid] = o > 0.f ? o : __expf(o) - 1.f;
    }
}

// ---------------------------------------------------------------------------
extern "C" void kernel_launch(void* const* d_in, const int* in_sizes, int n_in,
                              void* d_out, int out_size, void* d_ws, size_t ws_size,
                              hipStream_t stream) {
    const float* features   = (const float*)d_in[0];
    const float* W_enc      = (const float*)d_in[1];
    const float* b_enc      = (const float*)d_in[2];
    const float* W_att      = (const float*)d_in[3];
    const float* b_att      = (const float*)d_in[4];
    const float* w_mp       = (const float*)d_in[5];
    const float* b_mp       = (const float*)d_in[6];
    const int*   instances  = (const int*)d_in[7];
    const int*   edge_types = (const int*)d_in[8];
    float* out = (float*)d_out;
    float* ws  = (float*)d_ws;

    const int nblk = NPATH * BPP;                     // 768

    float* pV = ws;                                   // 768*128
    float* pM = pV + (size_t)nblk * DFEAT;            // 768
    float* pS = pM + nblk;                            // 768

    k_pass1<<<nblk, TPB1, 0, stream>>>(features, instances, W_enc, b_enc,
                                       W_att, b_att, edge_types, pV, pM, pS);

    k_tail<<<1, 512, 0, stream>>>(pV, pM, pS, W_enc, b_enc, w_mp, b_mp, out);
}

// Round 9
// 66.132 us; speedup vs baseline: 2.0788x; 2.0788x over previous
//
#include <hip/hip_runtime.h>
#include <hip/hip_bf16.h>
#include <math.h>

#define NPATH 6
#define NINST 20000
#define PLEN 4
#define DFEAT 128
#define TPB1 256            // threads per pass1 block
#define WPB 4               // waves per block
#define GPW 4               // instance-groups per wave (16 lanes each)
#define GPB (WPB * GPW)     // 16 groups per block
#define BPP 128             // blocks per path
#define GPP (BPP * GPB)     // 2048 instance streams per path
#define RESCALE_THR 8.0f

__device__ __forceinline__ float dot4(float4 a, float4 b) {
    return a.x * b.x + a.y * b.y + a.z * b.z + a.w * b.w;
}

// ---------------------------------------------------------------------------
// Pass 1: fused u-precompute + online-softmax gather, 2-deep software pipeline.
// 16-lane group owns one instance stream; lane sub holds dims [sub*4,+4) and
// [64+sub*4,+4). Main loop is guard-free (precise vmcnt, 8KB in flight/wave);
// 2-step epilogue consumes the last prefetched register sets.
// Defer-max online softmax: rescale only when tmax exceeds m_ref + 8.
// grid = NPATH*BPP x TPB1
// ---------------------------------------------------------------------------
__global__ __launch_bounds__(TPB1, 4) void k_pass1(
    const float* __restrict__ feat, const int* __restrict__ inst,
    const float* __restrict__ W_enc, const float* __restrict__ b_enc,
    const float* __restrict__ W_att, const float* __restrict__ b_att,
    const int* __restrict__ etype,
    float* __restrict__ pV, float* __restrict__ pM, float* __restrict__ pS)
{
    int m    = blockIdx.x / BPP;
    int bw   = blockIdx.x % BPP;
    int tid  = threadIdx.x;
    int wv   = tid >> 6, lane = tid & 63;
    int grp  = lane >> 4, sub = lane & 15;
    int gid  = wv * GPW + grp;              // group within block [0,16)
    int g    = bw * GPB + gid;              // stream id within path [0,2048)

    __shared__ float swa[2 * DFEAT];
    __shared__ float su1[DFEAT], su2[DFEAT];
    __shared__ float sbc[DFEAT];
    __shared__ float scv;
    __shared__ float sV[GPB][DFEAT + 4];
    __shared__ float sMx[GPB], sSm[GPB];

    // ---- prologue: issue idx + two row-sets immediately ----
    const int4* ib4 = (const int4*)(inst + (size_t)m * NINST * PLEN);
    int i = g;
    int4 j0 = ib4[i];
    int4 j1 = ib4[i + GPP];
    int4 j2 = ib4[i + 2 * GPP];             // g+4096 < 20000 always

    const float4* r0 = (const float4*)(feat + (size_t)j0.x * DFEAT);
    const float4* r3 = (const float4*)(feat + (size_t)j0.w * DFEAT);
    float4 A0a = r0[sub], A0b = r0[sub + 16];
    float4 A3a = r3[sub], A3b = r3[sub + 16];
    const float4* q0 = (const float4*)(feat + (size_t)j1.x * DFEAT);
    const float4* q3 = (const float4*)(feat + (size_t)j1.w * DFEAT);
    float4 B0a = q0[sub], B0b = q0[sub + 16];
    float4 B3a = q3[sub], B3b = q3[sub + 16];

    // ---- u1/u2/c in LDS (overlaps the in-flight gathers) ----
    int e = etype[m];
    swa[tid] = W_att[(size_t)e * (2 * DFEAT) + tid];    // TPB1 == 2*DFEAT
    __syncthreads();
    if (tid < DFEAT) {
        const float4* Wr = (const float4*)(W_enc + ((size_t)m * DFEAT + tid) * DFEAT);
        float s1 = 0.f, s2 = 0.f;
        #pragma unroll 8
        for (int q = 0; q < DFEAT / 4; ++q) {
            float4 w4 = Wr[q];
            s1 += w4.x * swa[4*q]         + w4.y * swa[4*q+1]
                + w4.z * swa[4*q+2]       + w4.w * swa[4*q+3];
            s2 += w4.x * swa[DFEAT+4*q]   + w4.y * swa[DFEAT+4*q+1]
                + w4.z * swa[DFEAT+4*q+2] + w4.w * swa[DFEAT+4*q+3];
        }
        su1[tid] = s1;
        su2[tid] = s2;
        sbc[tid] = b_enc[m * DFEAT + tid] * (swa[tid] + swa[DFEAT + tid]);
    }
    __syncthreads();
    if (tid < 64) {
        float t = sbc[tid] + sbc[tid + 64];
        #pragma unroll
        for (int o = 32; o; o >>= 1) t += __shfl_xor(t, o);
        if (tid == 0) scv = t + b_att[e];
    }
    __syncthreads();

    float4 U1a = ((const float4*)su1)[sub], U1b = ((const float4*)su1)[sub + 16];
    float4 U2a = ((const float4*)su2)[sub], U2b = ((const float4*)su2)[sub + 16];
    float c = scv;

    float mref = 0.f, tmax = -3e38f, sum = 0.f;
    float4 va = make_float4(0.f, 0.f, 0.f, 0.f);
    float4 vb = make_float4(0.f, 0.f, 0.f, 0.f);

#define COMPUTE(R0a, R0b, R3a, R3b)                                          \
    {                                                                        \
        float p = dot4(R0a, U1a) + dot4(R0b, U1b)                            \
                + dot4(R3a, U2a) + dot4(R3b, U2b);                           \
        p += __shfl_xor(p, 1);                                               \
        p += __shfl_xor(p, 2);                                               \
        p += __shfl_xor(p, 4);                                               \
        p += __shfl_xor(p, 8);                                               \
        float s = p + c;                                                     \
        s = s > 0.f ? s : 0.2f * s;                                          \
        tmax = fmaxf(tmax, s);                                               \
        if (tmax > mref + RESCALE_THR) {                                     \
            float r = __expf(mref - tmax);                                   \
            sum *= r;                                                        \
            va.x *= r; va.y *= r; va.z *= r; va.w *= r;                      \
            vb.x *= r; vb.y *= r; vb.z *= r; vb.w *= r;                      \
            mref = tmax;                                                     \
        }                                                                    \
        float pe = __expf(s - mref);                                         \
        sum += pe;                                                           \
        va.x += pe * R3a.x; va.y += pe * R3a.y;                              \
        va.z += pe * R3a.z; va.w += pe * R3a.w;                              \
        vb.x += pe * R3b.x; vb.y += pe * R3b.y;                              \
        vb.z += pe * R3b.z; vb.w += pe * R3b.w;                              \
    }

    // ---- guard-free main loop: rows for i+2G prefetched unconditionally ----
    while (i + 2 * GPP < NINST) {
        const float4* p0 = (const float4*)(feat + (size_t)j2.x * DFEAT);
        const float4* p3 = (const float4*)(feat + (size_t)j2.w * DFEAT);
        float4 C0a = p0[sub], C0b = p0[sub + 16];
        float4 C3a = p3[sub], C3b = p3[sub + 16];
        int nj = i + 3 * GPP;
        nj = nj < NINST ? nj : NINST - 1;   // clamped idx prefetch (16B, harmless)
        int4 j3 = ib4[nj];

        COMPUTE(A0a, A0b, A3a, A3b);

        A0a = B0a; A0b = B0b; A3a = B3a; A3b = B3b;
        B0a = C0a; B0b = C0b; B3a = C3a; B3b = C3b;
        j2 = j3;
        i += GPP;
    }

    // ---- epilogue: 2 remaining instances, rows already in registers ----
    COMPUTE(A0a, A0b, A3a, A3b);
    i += GPP;
    if (i < NINST) COMPUTE(B0a, B0b, B3a, B3b);

#undef COMPUTE

    // ---- block-level flash combine of 16 group states ----
    *(float4*)&sV[gid][sub * 4]      = va;
    *(float4*)&sV[gid][64 + sub * 4] = vb;
    if (sub == 0) { sMx[gid] = mref; sSm[gid] = sum; }
    __syncthreads();

    if (tid < DFEAT) {
        float M = sMx[0];
        #pragma unroll
        for (int k = 1; k < GPB; ++k) M = fmaxf(M, sMx[k]);
        float S = 0.f, V = 0.f;
        #pragma unroll
        for (int k = 0; k < GPB; ++k) {
            float ek = __expf(sMx[k] - M);
            S += ek * sSm[k];
            V += ek * sV[k][tid];
        }
        pV[(size_t)blockIdx.x * DFEAT + tid] = V;
        if (tid == 0) { pM[blockIdx.x] = M; pS[blockIdx.x] = S; }
    }
}

// ---------------------------------------------------------------------------
// Pass 2: per path — flash-combine 128 block partials, normalize, GEMV with
// W_enc, produce mp_out[m][:] and ms[m].  grid = 6 x 256
// ---------------------------------------------------------------------------
__global__ __launch_bounds__(256) void k_pass2(
    const float* __restrict__ pV, const float* __restrict__ pM, const float* __restrict__ pS,
    const float* __restrict__ W_enc, const float* __restrict__ b_enc,
    const float* __restrict__ w_mp, const float* __restrict__ b_mp,
    float* __restrict__ mp_out, float* __restrict__ ms)
{
    int m = blockIdx.x, tid = threadIdx.x;
    int d = tid & 127, slice = tid >> 7;    // 2 slices

    __shared__ float tmp[BPP];
    __shared__ float eL[BPP];
    __shared__ float sv[2][DFEAT];
    __shared__ float sVn[DFEAT];
    __shared__ float smp[DFEAT];
    __shared__ float sS, sMx;

    if (tid < BPP) tmp[tid] = pM[m * BPP + tid];
    __syncthreads();
    for (int off = 64; off; off >>= 1) {
        if (tid < off) tmp[tid] = fmaxf(tmp[tid], tmp[tid + off]);
        __syncthreads();
    }
    if (tid == 0) sMx = tmp[0];
    __syncthreads();
    float M = sMx;

    if (tid < BPP) {
        float ek = __expf(pM[m * BPP + tid] - M);
        eL[tid] = ek;
        tmp[tid] = ek * pS[m * BPP + tid];
    }
    __syncthreads();
    for (int off = 64; off; off >>= 1) {
        if (tid < off) tmp[tid] += tmp[tid + off];
        __syncthreads();
    }
    if (tid == 0) sS = tmp[0];
    __syncthreads();
    float Sinv = 1.f / sS;

    float acc = 0.f;
    for (int k = slice; k < BPP; k += 2)
        acc += eL[k] * pV[((size_t)(m * BPP + k)) * DFEAT + d];
    sv[slice][d] = acc;
    __syncthreads();
    if (tid < DFEAT) sVn[tid] = (sv[0][tid] + sv[1][tid]) * Sinv;
    __syncthreads();

    const float* W = W_enc + (size_t)m * DFEAT * DFEAT;
    float gacc = 0.f;
    for (int dd = slice; dd < DFEAT; dd += 2)
        gacc += sVn[dd] * W[(size_t)dd * DFEAT + d];
    __syncthreads();
    sv[slice][d] = gacc;
    __syncthreads();
    if (tid < DFEAT) {
        float t = sv[0][tid] + sv[1][tid] + b_enc[m * DFEAT + tid];
        mp_out[m * DFEAT + tid] = t;
        smp[tid] = t * w_mp[tid];
    }
    __syncthreads();

    if (tid < 64) {
        float t = smp[tid] + smp[tid + 64];
        #pragma unroll
        for (int o = 32; o; o >>= 1) t += __shfl_xor(t, o);
        if (tid == 0) ms[m] = t + b_mp[0];
    }
}

// ---------------------------------------------------------------------------
// Pass 3: cross-path softmax(leaky_relu(ms)) + blend + ELU.  1 block x 128.
// ---------------------------------------------------------------------------
__global__ void k_final(const float* __restrict__ mp_out, const float* __restrict__ ms,
                        float* __restrict__ out) {
    int h = threadIdx.x;
    float l[NPATH], mx = -3e38f;
    #pragma unroll
    for (int m = 0; m < NPATH; ++m) {
        float x = ms[m];
        x = x > 0.f ? x : 0.2f * x;
        l[m] = x;
        mx = fmaxf(mx, x);
    }
    float sum = 0.f;
    #pragma unroll
    for (int m = 0; m < NPATH; ++m) { l[m] = __expf(l[m] - mx); sum += l[m]; }
    float o = 0.f;
    #pragma unroll
    for (int m = 0; m < NPATH; ++m) o += (l[m] / sum) * mp_out[m * DFEAT + h];
    out[h] = o > 0.f ? o : __expf(o) - 1.f;   // elu
}

// ---------------------------------------------------------------------------
extern "C" void kernel_launch(void* const* d_in, const int* in_sizes, int n_in,
                              void* d_out, int out_size, void* d_ws, size_t ws_size,
                              hipStream_t stream) {
    const float* features   = (const float*)d_in[0];
    const float* W_enc      = (const float*)d_in[1];
    const float* b_enc      = (const float*)d_in[2];
    const float* W_att      = (const float*)d_in[3];
    const float* b_att      = (const float*)d_in[4];
    const float* w_mp       = (const float*)d_in[5];
    const float* b_mp       = (const float*)d_in[6];
    const int*   instances  = (const int*)d_in[7];
    const int*   edge_types = (const int*)d_in[8];
    float* out = (float*)d_out;
    float* ws  = (float*)d_ws;

    const int nblk1 = NPATH * BPP;                    // 768

    float* pV     = ws;                               // 768*128
    float* pM     = pV + (size_t)nblk1 * DFEAT;       // 768
    float* pS     = pM + nblk1;                       // 768
    float* mp_out = pS + nblk1;                       // 768
    float* msv    = mp_out + NPATH * DFEAT;           // 6

    k_pass1<<<nblk1, TPB1, 0, stream>>>(features, instances, W_enc, b_enc,
                                        W_att, b_att, edge_types, pV, pM, pS);

    k_pass2<<<NPATH, 256, 0, stream>>>(pV, pM, pS, W_enc, b_enc, w_mp, b_mp, mp_out, msv);

    k_final<<<1, DFEAT, 0, stream>>>(mp_out, msv, out);
}